// Round 9
// baseline (210.120 us; speedup 1.0000x reference)
//
#include <hip/hip_runtime.h>

#define T_SEQ 2048
#define MDL   1024
#define NH    8
#define HD    128

typedef __bf16 bf16;
typedef __bf16 bf16x8 __attribute__((ext_vector_type(8)));
typedef __bf16 bf16x4 __attribute__((ext_vector_type(4)));
typedef float  f32x4  __attribute__((ext_vector_type(4)));

#define GLB(p) ((const __attribute__((address_space(1))) void*)(p))
#define LDS(p) ((__attribute__((address_space(3))) void*)(p))

#if __has_builtin(__builtin_amdgcn_exp2f)
#define EXP2(x) __builtin_amdgcn_exp2f(x)
#else
#define EXP2(x) __expf((x) * 0.6931471805599453f)
#endif

// Q is pre-scaled by 2^-7 * log2(e) so attention P = exp2(QK) directly.
#define QSCALE 0.011271055f

// K image per (bh, jt<32): [d>>3][t&63][d&7]          (8192 elems)
// V image per (bh, jt<32): [p>>3][d][p&7], p = 4*(t&15) + (t>>4)  (j-permuted)

// ---------------------------------------------------------------------------
// Prep (fused): blocks < 2048: x fp32 -> bf16; blocks >= 2048: weight
// transpose-convert to bf16 B^T (n-major, k-contiguous).
// ---------------------------------------------------------------------------
__global__ __launch_bounds__(256) void prep_kernel(
    const float* __restrict__ x,
    const float* __restrict__ wq, const float* __restrict__ wk,
    const float* __restrict__ wv, const float* __restrict__ wo,
    bf16* __restrict__ xb, bf16* __restrict__ Wt, bf16* __restrict__ Wot)
{
    __shared__ bf16 t_lds[64 * 72];
    const int tid = threadIdx.x;
    if (blockIdx.x < 2048) {
        size_t i = ((size_t)blockIdx.x * 256 + tid) * 8;
        float4 v0 = *(const float4*)(x + i);
        float4 v1 = *(const float4*)(x + i + 4);
        bf16x8 o;
        o[0]=(bf16)v0.x; o[1]=(bf16)v0.y; o[2]=(bf16)v0.z; o[3]=(bf16)v0.w;
        o[4]=(bf16)v1.x; o[5]=(bf16)v1.y; o[6]=(bf16)v1.z; o[7]=(bf16)v1.w;
        *(bf16x8*)(xb + i) = o;
        return;
    }
    const int bx = blockIdx.x - 2048;
    const int sec = bx >> 8;
    const int tile = bx & 255;
    const int k0 = (tile >> 4) * 64, n0 = (tile & 15) * 64;
    const float* src = sec == 0 ? wq : sec == 1 ? wk : sec == 2 ? wv : wo;
    bf16* dst = sec < 3 ? (Wt + (size_t)sec * MDL * MDL) : Wot;

    const int ir = tid >> 2, jc = (tid & 3) * 16;
    const float* sp = src + (size_t)(k0 + ir) * MDL + n0 + jc;
    #pragma unroll
    for (int c = 0; c < 4; ++c) {
        float4 v = *(const float4*)(sp + c * 4);
        bf16x4 o; o[0]=(bf16)v.x; o[1]=(bf16)v.y; o[2]=(bf16)v.z; o[3]=(bf16)v.w;
        *(bf16x4*)&t_lds[ir * 72 + jc + c * 4] = o;
    }
    __syncthreads();
    bf16x8 o0, o1;
    #pragma unroll
    for (int jj = 0; jj < 8; ++jj) {
        o0[jj] = t_lds[(jc + jj) * 72 + ir];
        o1[jj] = t_lds[(jc + 8 + jj) * 72 + ir];
    }
    bf16* dp = dst + (size_t)(n0 + ir) * MDL + k0 + jc;
    *(bf16x8*)dp = o0;
    *(bf16x8*)(dp + 8) = o1;
}

// ---------------------------------------------------------------------------
// Kernel 1: QKV GEMM (m97 structure) + fused RoPE.
// Q (pre-scaled by QSCALE) -> [B,H,T,D]; K,V -> tile-image layouts.
// ---------------------------------------------------------------------------
__global__ __launch_bounds__(256) void qkv_rope_kernel(
    const bf16* __restrict__ xb, const bf16* __restrict__ Wt,
    bf16* __restrict__ Qb, bf16* __restrict__ Kt, bf16* __restrict__ Vt)
{
    __shared__ bf16 smem[8192];        // a_lds | b_lds; reused by epilogues
    bf16* a_lds = smem;
    bf16* b_lds = smem + 4096;

    const int tid = threadIdx.x, bx = blockIdx.x;
    const int nt = bx % 24, mt = bx / 24;
    const int n0 = nt * 128, m0 = mt * 128;
    const int section = n0 >> 10;
    const int h = (n0 & 1023) >> 7;

    const int lane = tid & 63, w = tid >> 6;
    const int quad = lane >> 4, l15 = lane & 15;
    const int wr = w >> 1, wc = w & 1;
    const int lrow = lane >> 2, lsub = lane & 3;

    const bf16* gA = xb + (size_t)m0 * MDL + lsub * 8;
    const bf16* gB = Wt + (size_t)n0 * MDL + lsub * 8;

    f32x4 acc[4][4] = {};

    for (int k0 = 0; k0 < MDL; k0 += 32) {
        #pragma unroll
        for (int i = 0; i < 2; ++i) {
            const int ch = w * 2 + i;
            const int row = ch * 16 + lrow;
            __builtin_amdgcn_global_load_lds(GLB(gA + (size_t)row * MDL + k0),
                                             LDS(&a_lds[ch * 16 * 32]), 16, 0, 0);
            __builtin_amdgcn_global_load_lds(GLB(gB + (size_t)row * MDL + k0),
                                             LDS(&b_lds[ch * 16 * 32]), 16, 0, 0);
        }
        __syncthreads();

        bf16x8 af[4], bfr[4];
        #pragma unroll
        for (int mi = 0; mi < 4; ++mi)
            af[mi] = *(const bf16x8*)&a_lds[(wr * 64 + mi * 16 + l15) * 32 + quad * 8];
        #pragma unroll
        for (int ni = 0; ni < 4; ++ni)
            bfr[ni] = *(const bf16x8*)&b_lds[(wc * 64 + ni * 16 + l15) * 32 + quad * 8];
        #pragma unroll
        for (int mi = 0; mi < 4; ++mi)
            #pragma unroll
            for (int ni = 0; ni < 4; ++ni)
                acc[mi][ni] = __builtin_amdgcn_mfma_f32_16x16x32_bf16(af[mi], bfr[ni], acc[mi][ni], 0, 0, 0);
        __syncthreads();
    }

    const int bdx = m0 >> 11;
    const int t0 = m0 & (T_SEQ - 1);
    const int bh = bdx * NH + h;

    if (section == 2) {
        // ---- V -> j-permuted image via LDS, linear coalesced out ----
        #pragma unroll
        for (int c = 0; c < 2; ++c) {
            if (wc == c) {
                #pragma unroll
                for (int mi = 0; mi < 4; ++mi)
                    #pragma unroll
                    for (int r = 0; r < 4; ++r) {
                        int p = 16 * quad + 4 * r + mi;       // permuted pos
                        int base = (wr * 8 + (p >> 3)) * 512 + (p & 7);
                        #pragma unroll
                        for (int ni = 0; ni < 4; ++ni)
                            smem[base + (ni * 16 + l15) * 8] = (bf16)acc[mi][ni][r];
                    }
            }
            __syncthreads();
            {
                const int t8 = tid >> 4;
                bf16* vp = Vt + ((size_t)(bh * 32 + (t0 >> 6) + (t8 >> 3))) * 8192
                              + (t8 & 7) * 1024 + c * 512 + (tid & 15) * 32;
                #pragma unroll
                for (int k = 0; k < 4; ++k)
                    *(bf16x8*)(vp + k * 8) = *(const bf16x8*)&smem[tid * 32 + k * 8];
            }
            __syncthreads();
        }
        return;
    }

    float fr_n[2];
    #pragma unroll
    for (int ni = 0; ni < 2; ++ni)
        fr_n[ni] = __expf(-(float)(ni * 16 + l15) * 0.28782313662425573f);

    if (section == 0) {
        // ---- Q: [bh][t][d], RoPE on d<64, all scaled by QSCALE ----
        #pragma unroll
        for (int mi = 0; mi < 4; ++mi) {
            #pragma unroll
            for (int r = 0; r < 4; ++r) {
                int t = t0 + wr * 64 + mi * 16 + quad * 4 + r;
                bf16* orow = Qb + ((size_t)bh * T_SEQ + t) * HD;
                if (wc == 0) {
                    #pragma unroll
                    for (int ni = 0; ni < 2; ++ni) {
                        int d = ni * 16 + l15;
                        float ang = (float)t * fr_n[ni];
                        float sn = __sinf(ang), cs = __cosf(ang);
                        float ev = acc[mi][ni][r];
                        float ov = acc[mi][ni + 2][r];
                        orow[d]      = (bf16)((ev * cs - ov * sn) * QSCALE);
                        orow[d + 32] = (bf16)((ev * sn + ov * cs) * QSCALE);
                    }
                } else {
                    #pragma unroll
                    for (int ni = 0; ni < 4; ++ni)
                        orow[64 + ni * 16 + l15] = (bf16)(acc[mi][ni][r] * QSCALE);
                }
            }
        }
    } else {
        // ---- K -> image via LDS (half = one 64-t jt tile), RoPE fused ----
        #pragma unroll
        for (int c = 0; c < 2; ++c) {
            if (wr == c) {
                #pragma unroll
                for (int mi = 0; mi < 4; ++mi) {
                    #pragma unroll
                    for (int r = 0; r < 4; ++r) {
                        int tl = mi * 16 + quad * 4 + r;
                        int t = t0 + c * 64 + tl;
                        if (wc == 0) {
                            #pragma unroll
                            for (int ni = 0; ni < 2; ++ni) {
                                int d = ni * 16 + l15;
                                float ang = (float)t * fr_n[ni];
                                float sn = __sinf(ang), cs = __cosf(ang);
                                float ev = acc[mi][ni][r];
                                float ov = acc[mi][ni + 2][r];
                                smem[(d >> 3) * 512 + tl * 8 + (d & 7)] = (bf16)(ev * cs - ov * sn);
                                int d2 = d + 32;
                                smem[(d2 >> 3) * 512 + tl * 8 + (d2 & 7)] = (bf16)(ev * sn + ov * cs);
                            }
                        } else {
                            #pragma unroll
                            for (int ni = 0; ni < 4; ++ni) {
                                int d = 64 + ni * 16 + l15;
                                smem[(d >> 3) * 512 + tl * 8 + (d & 7)] = (bf16)acc[mi][ni][r];
                            }
                        }
                    }
                }
            }
            __syncthreads();
            {
                bf16* kp = Kt + ((size_t)(bh * 32 + (t0 >> 6) + c)) * 8192 + tid * 32;
                #pragma unroll
                for (int k = 0; k < 4; ++k)
                    *(bf16x8*)(kp + k * 8) = *(const bf16x8*)&smem[tid * 32 + k * 8];
            }
            __syncthreads();
        }
    }
}

// ---------------------------------------------------------------------------
// Kernel 2: BARRIER-FREE causal flash attention. Each wave is independent:
// 32 q-rows, every-4th KV tile of the balanced q-pair {m, 63-m}; K/V
// fragments load global->VGPR directly from L2-resident images (no staging
// LDS, no per-step __syncthreads). P round-trips a per-wave private LDS
// slice (same-wave lgkm ordering). Intra-block LDS combine of the 4 split
// partials at each q-tile end -> direct Ob store (no combine kernel).
// NOTE: l_r must be shuffle-reduced over the 16 l15 lanes before the
// combine (R8 bug: raw per-lane partial stored -> 13.6 absmax).
// ---------------------------------------------------------------------------
__global__ __launch_bounds__(256, 2) void attn_kernel(
    const bf16* __restrict__ Qb, const bf16* __restrict__ Kt,
    const bf16* __restrict__ Vt, bf16* __restrict__ Ob)
{
    __shared__ bf16 p_lds[4][32 * 72];     // per-wave P [32 rows][64+pad]
    __shared__ bf16 slot[4][128 * 32];     // combine: [col][row] per wave
    __shared__ float lsl[4][32];           // combine: row sums

    const int tid = threadIdx.x, lane = tid & 63, w = tid >> 6;
    const int quad = lane >> 4, l15 = lane & 15;
    const int bx = blockIdx.x;
    const int m  = bx & 31;                // pair {m, 63-m} of 32-row q-tiles
    const int bh = bx >> 5;
    const int b = bh >> 3, h = bh & 7;

    const bf16* Kbh = Kt + (size_t)bh * 32 * 8192;
    const bf16* Vbh = Vt + (size_t)bh * 32 * 8192;

    bf16x8 kb[4][4];       // K fragments, full tile, prefetched 1 step ahead
    bf16x8 vb[8];          // V fragments, half-tile batches
    bf16x8 qf[2][4];
    f32x4 Of[2][8];
    float l_r[2][4];

    const bf16* kbase = Kbh + (size_t)quad * 512 + (size_t)l15 * 8;
    const bf16* vbase = Vbh + (size_t)quad * 1024 + (size_t)l15 * 8;

    auto issue_k = [&](int j) {
        const bf16* kt = kbase + (size_t)j * 8192;
        #pragma unroll
        for (int kk = 0; kk < 4; ++kk)
            #pragma unroll
            for (int ni = 0; ni < 4; ++ni)
                kb[kk][ni] = *(const bf16x8*)(kt + kk * 2048 + ni * 128);
    };
    auto issue_v = [&](int j, int half) {
        const bf16* vt = vbase + (size_t)j * 8192 + half * 4096;
        #pragma unroll
        for (int di = 0; di < 8; ++di)
            vb[di] = *(const bf16x8*)(vt + di * 128);
    };

    #pragma unroll 1
    for (int phase = 0; phase < 2; ++phase) {
        const int qt = phase ? m : 63 - m;     // 32-row q-tile index (0..63)
        const int cnt = (qt >> 1) + 1;         // KV 64-tiles needed
        const int dj = qt >> 1;                // diagonal tile

        #pragma unroll
        for (int mi = 0; mi < 2; ++mi) {
            const bf16* qr = Qb + ((size_t)bh * T_SEQ + qt * 32 + mi * 16 + l15) * HD + quad * 8;
            #pragma unroll
            for (int kk = 0; kk < 4; ++kk)
                qf[mi][kk] = *(const bf16x8*)(qr + kk * 32);
            #pragma unroll
            for (int di = 0; di < 8; ++di) Of[mi][di] = (f32x4){0.f, 0.f, 0.f, 0.f};
            #pragma unroll
            for (int r = 0; r < 4; ++r) l_r[mi][r] = 0.f;
        }

        if (w < cnt) issue_k(w);

        #pragma unroll 1
        for (int jt = w; jt < cnt; jt += 4) {
            // ---- S = Q K^T (32 q-rows x 64 kv-cols) ----
            f32x4 sa[2][4] = {};
            #pragma unroll
            for (int kk = 0; kk < 4; ++kk)
                #pragma unroll
                for (int ni = 0; ni < 4; ++ni)
                    #pragma unroll
                    for (int mi = 0; mi < 2; ++mi)
                        sa[mi][ni] = __builtin_amdgcn_mfma_f32_16x16x32_bf16(qf[mi][kk], kb[kk][ni], sa[mi][ni], 0, 0, 0);

            if (jt + 4 < cnt) issue_k(jt + 4);   // next K flies under softmax+PV
            issue_v(jt, 0);                      // current V, first half

            // ---- P = exp2(S), causal mask on the diagonal tile ----
            const bool diag = (jt == dj);
            #pragma unroll
            for (int mi = 0; mi < 2; ++mi) {
                #pragma unroll
                for (int r = 0; r < 4; ++r) {
                    const int rowg = qt * 32 + mi * 16 + quad * 4 + r;
                    float ps = 0.f;
                    bf16x4 pq;
                    #pragma unroll
                    for (int ni = 0; ni < 4; ++ni) {
                        float pv = EXP2(sa[mi][ni][r]);
                        if (diag && (jt * 64 + ni * 16 + l15) > rowg) pv = 0.f;
                        ps += pv;
                        pq[ni] = (bf16)pv;
                    }
                    // j-permuted store: cols l15*4..+3 (one b64)
                    *(bf16x4*)&p_lds[w][(mi * 16 + quad * 4 + r) * 72 + l15 * 4] = pq;
                    l_r[mi][r] += ps;
                }
            }

            // ---- O += P V (V image shares the j-permutation) ----
            bf16x8 pa[2];
            #pragma unroll
            for (int mi = 0; mi < 2; ++mi)
                pa[mi] = *(const bf16x8*)&p_lds[w][(mi * 16 + l15) * 72 + quad * 8];
            #pragma unroll
            for (int di = 0; di < 8; ++di)
                #pragma unroll
                for (int mi = 0; mi < 2; ++mi)
                    Of[mi][di] = __builtin_amdgcn_mfma_f32_16x16x32_bf16(pa[mi], vb[di], Of[mi][di], 0, 0, 0);

            issue_v(jt, 1);                      // second half
            #pragma unroll
            for (int mi = 0; mi < 2; ++mi)
                pa[mi] = *(const bf16x8*)&p_lds[w][(mi * 16 + l15) * 72 + 32 + quad * 8];
            #pragma unroll
            for (int di = 0; di < 8; ++di)
                #pragma unroll
                for (int mi = 0; mi < 2; ++mi)
                    Of[mi][di] = __builtin_amdgcn_mfma_f32_16x16x32_bf16(pa[mi], vb[di], Of[mi][di], 0, 0, 0);
        }

        // ---- intra-block combine of 4 split partials, direct Ob store ----
        __syncthreads();                         // all waves done with steps
        #pragma unroll
        for (int mi = 0; mi < 2; ++mi)
            #pragma unroll
            for (int di = 0; di < 8; ++di) {
                bf16x4 t;
                #pragma unroll
                for (int r = 0; r < 4; ++r) t[r] = (bf16)Of[mi][di][r];
                *(bf16x4*)&slot[w][(di * 16 + l15) * 32 + mi * 16 + quad * 4] = t;
            }
        #pragma unroll
        for (int mi = 0; mi < 2; ++mi)
            #pragma unroll
            for (int r = 0; r < 4; ++r) {
                float ls = l_r[mi][r];
                ls += __shfl_xor(ls, 1); ls += __shfl_xor(ls, 2);
                ls += __shfl_xor(ls, 4); ls += __shfl_xor(ls, 8);
                if (l15 == 0) lsl[w][mi * 16 + quad * 4 + r] = ls;
            }
        __syncthreads();                         // slots visible
        {
            const int row = tid >> 3;            // 0..31
            const int dc = (tid & 7) * 16;       // 16 d-cols
            float av[16] = {};
            float l = 0.f;
            #pragma unroll
            for (int s = 0; s < 4; ++s) {
                l += lsl[s][row];
                #pragma unroll
                for (int c = 0; c < 16; ++c)
                    av[c] += (float)slot[s][(dc + c) * 32 + row];
            }
            const float inv = 1.f / l;
            const int t = qt * 32 + row;
            bf16* op = Ob + ((size_t)(b * T_SEQ + t) * NH + h) * HD + dc;
            bf16x8 o0, o1;
            #pragma unroll
            for (int c = 0; c < 8; ++c) { o0[c] = (bf16)(av[c] * inv); o1[c] = (bf16)(av[c + 8] * inv); }
            *(bf16x8*)op = o0;
            *(bf16x8*)(op + 8) = o1;
        }
        __syncthreads();                         // slots reusable next phase
    }
}

// ---------------------------------------------------------------------------
// Kernel 3: output projection, m97 structure. R = Ob @ Wot^T, fp32 out.
// ---------------------------------------------------------------------------
__global__ __launch_bounds__(256) void out_proj_kernel(
    const bf16* __restrict__ Ob, const bf16* __restrict__ Wot,
    float* __restrict__ out)
{
    __shared__ bf16 a_lds[128 * 32];
    __shared__ bf16 b_lds[128 * 32];

    const int tid = threadIdx.x, bx = blockIdx.x;
    const int nt = bx & 7, mt = bx >> 3;
    const int n0 = nt * 128, m0 = mt * 128;

    const int lane = tid & 63, w = tid >> 6;
    const int quad = lane >> 4, l15 = lane & 15;
    const int wr = w >> 1, wc = w & 1;
    const int lrow = lane >> 2, lsub = lane & 3;

    const bf16* gA = Ob  + (size_t)m0 * MDL + lsub * 8;
    const bf16* gB = Wot + (size_t)n0 * MDL + lsub * 8;

    f32x4 acc[4][4] = {};

    for (int k0 = 0; k0 < MDL; k0 += 32) {
        #pragma unroll
        for (int i = 0; i < 2; ++i) {
            const int ch = w * 2 + i;
            const int row = ch * 16 + lrow;
            __builtin_amdgcn_global_load_lds(GLB(gA + (size_t)row * MDL + k0),
                                             LDS(&a_lds[ch * 16 * 32]), 16, 0, 0);
            __builtin_amdgcn_global_load_lds(GLB(gB + (size_t)row * MDL + k0),
                                             LDS(&b_lds[ch * 16 * 32]), 16, 0, 0);
        }
        __syncthreads();

        bf16x8 af[4], bfr[4];
        #pragma unroll
        for (int mi = 0; mi < 4; ++mi)
            af[mi] = *(const bf16x8*)&a_lds[(wr * 64 + mi * 16 + l15) * 32 + quad * 8];
        #pragma unroll
        for (int ni = 0; ni < 4; ++ni)
            bfr[ni] = *(const bf16x8*)&b_lds[(wc * 64 + ni * 16 + l15) * 32 + quad * 8];
        #pragma unroll
        for (int mi = 0; mi < 4; ++mi)
            #pragma unroll
            for (int ni = 0; ni < 4; ++ni)
                acc[mi][ni] = __builtin_amdgcn_mfma_f32_16x16x32_bf16(af[mi], bfr[ni], acc[mi][ni], 0, 0, 0);
        __syncthreads();
    }

    #pragma unroll
    for (int mi = 0; mi < 4; ++mi)
        #pragma unroll
        for (int r = 0; r < 4; ++r) {
            int row_g = m0 + wr * 64 + mi * 16 + quad * 4 + r;
            float* crow = out + (size_t)row_g * MDL + n0;
            #pragma unroll
            for (int ni = 0; ni < 4; ++ni)
                crow[wc * 64 + ni * 16 + l15] = acc[mi][ni][r];
        }
}

// ---------------------------------------------------------------------------
extern "C" void kernel_launch(void* const* d_in, const int* in_sizes, int n_in,
                              void* d_out, int out_size, void* d_ws, size_t ws_size,
                              hipStream_t stream) {
    const float* x  = (const float*)d_in[0];
    const float* wq = (const float*)d_in[1];
    const float* wk = (const float*)d_in[2];
    const float* wv = (const float*)d_in[3];
    const float* wo = (const float*)d_in[4];
    float* out = (float*)d_out;

    const size_t NTOK = (size_t)2 * NH * T_SEQ * HD;  // 4,194,304 elems
    bf16*  Qb  = (bf16*)d_ws;
    bf16*  Kt  = Qb + NTOK;
    bf16*  Vt  = Kt + NTOK;
    bf16*  Ob  = Vt + NTOK;
    bf16*  Wot = Ob + NTOK;                           // 1 M elems

    // xb / Wt scratch live inside d_out (16 MB) — dead before out_proj writes.
    bf16* xbuf = (bf16*)d_out;
    bf16* Wt   = xbuf + (size_t)4096 * MDL;

    prep_kernel<<<3072, 256, 0, stream>>>(x, wq, wk, wv, wo, xbuf, Wt, Wot);
    qkv_rope_kernel<<<768, 256, 0, stream>>>(xbuf, Wt, Qb, Kt, Vt);
    attn_kernel<<<512, 256, 0, stream>>>(Qb, Kt, Vt, Ob);
    out_proj_kernel<<<256, 256, 0, stream>>>(Ob, Wot, out);
}

// Round 10
// 206.808 us; speedup vs baseline: 1.0160x; 1.0160x over previous
//
#include <hip/hip_runtime.h>

#define T_SEQ 2048
#define MDL   1024
#define NH    8
#define HD    128

typedef __bf16 bf16;
typedef __bf16 bf16x8 __attribute__((ext_vector_type(8)));
typedef __bf16 bf16x4 __attribute__((ext_vector_type(4)));
typedef float  f32x4  __attribute__((ext_vector_type(4)));

#define GLB(p) ((const __attribute__((address_space(1))) void*)(p))
#define LDS(p) ((__attribute__((address_space(3))) void*)(p))

#if __has_builtin(__builtin_amdgcn_exp2f)
#define EXP2(x) __builtin_amdgcn_exp2f(x)
#else
#define EXP2(x) __expf((x) * 0.6931471805599453f)
#endif

// Q is pre-scaled by 2^-7 * log2(e) so attention P = exp2(QK) directly.
#define QSCALE 0.011271055f

// K image per (bh, jt<32): [d>>3][t&63][d&7]          (8192 elems)
// V image per (bh, jt<32): [p>>3][d][p&7], p = 4*(t&15) + (t>>4)  (j-permuted)

// ---------------------------------------------------------------------------
// Prep (fused): blocks < 2048: x fp32 -> bf16; blocks >= 2048: weight
// transpose-convert to bf16 B^T (n-major, k-contiguous).
// ---------------------------------------------------------------------------
__global__ __launch_bounds__(256) void prep_kernel(
    const float* __restrict__ x,
    const float* __restrict__ wq, const float* __restrict__ wk,
    const float* __restrict__ wv, const float* __restrict__ wo,
    bf16* __restrict__ xb, bf16* __restrict__ Wt, bf16* __restrict__ Wot)
{
    __shared__ bf16 t_lds[64 * 72];
    const int tid = threadIdx.x;
    if (blockIdx.x < 2048) {
        size_t i = ((size_t)blockIdx.x * 256 + tid) * 8;
        float4 v0 = *(const float4*)(x + i);
        float4 v1 = *(const float4*)(x + i + 4);
        bf16x8 o;
        o[0]=(bf16)v0.x; o[1]=(bf16)v0.y; o[2]=(bf16)v0.z; o[3]=(bf16)v0.w;
        o[4]=(bf16)v1.x; o[5]=(bf16)v1.y; o[6]=(bf16)v1.z; o[7]=(bf16)v1.w;
        *(bf16x8*)(xb + i) = o;
        return;
    }
    const int bx = blockIdx.x - 2048;
    const int sec = bx >> 8;
    const int tile = bx & 255;
    const int k0 = (tile >> 4) * 64, n0 = (tile & 15) * 64;
    const float* src = sec == 0 ? wq : sec == 1 ? wk : sec == 2 ? wv : wo;
    bf16* dst = sec < 3 ? (Wt + (size_t)sec * MDL * MDL) : Wot;

    const int ir = tid >> 2, jc = (tid & 3) * 16;
    const float* sp = src + (size_t)(k0 + ir) * MDL + n0 + jc;
    #pragma unroll
    for (int c = 0; c < 4; ++c) {
        float4 v = *(const float4*)(sp + c * 4);
        bf16x4 o; o[0]=(bf16)v.x; o[1]=(bf16)v.y; o[2]=(bf16)v.z; o[3]=(bf16)v.w;
        *(bf16x4*)&t_lds[ir * 72 + jc + c * 4] = o;
    }
    __syncthreads();
    bf16x8 o0, o1;
    #pragma unroll
    for (int jj = 0; jj < 8; ++jj) {
        o0[jj] = t_lds[(jc + jj) * 72 + ir];
        o1[jj] = t_lds[(jc + 8 + jj) * 72 + ir];
    }
    bf16* dp = dst + (size_t)(n0 + ir) * MDL + k0 + jc;
    *(bf16x8*)dp = o0;
    *(bf16x8*)(dp + 8) = o1;
}

// ---------------------------------------------------------------------------
// Kernel 1: QKV GEMM (m97 structure) + fused RoPE.
// Q (pre-scaled by QSCALE) -> [B,H,T,D]; K,V -> tile-image layouts.
// ---------------------------------------------------------------------------
__global__ __launch_bounds__(256) void qkv_rope_kernel(
    const bf16* __restrict__ xb, const bf16* __restrict__ Wt,
    bf16* __restrict__ Qb, bf16* __restrict__ Kt, bf16* __restrict__ Vt)
{
    __shared__ bf16 smem[8192];        // a_lds | b_lds; reused by epilogues
    bf16* a_lds = smem;
    bf16* b_lds = smem + 4096;

    const int tid = threadIdx.x, bx = blockIdx.x;
    const int nt = bx % 24, mt = bx / 24;
    const int n0 = nt * 128, m0 = mt * 128;
    const int section = n0 >> 10;
    const int h = (n0 & 1023) >> 7;

    const int lane = tid & 63, w = tid >> 6;
    const int quad = lane >> 4, l15 = lane & 15;
    const int wr = w >> 1, wc = w & 1;
    const int lrow = lane >> 2, lsub = lane & 3;

    const bf16* gA = xb + (size_t)m0 * MDL + lsub * 8;
    const bf16* gB = Wt + (size_t)n0 * MDL + lsub * 8;

    f32x4 acc[4][4] = {};

    for (int k0 = 0; k0 < MDL; k0 += 32) {
        #pragma unroll
        for (int i = 0; i < 2; ++i) {
            const int ch = w * 2 + i;
            const int row = ch * 16 + lrow;
            __builtin_amdgcn_global_load_lds(GLB(gA + (size_t)row * MDL + k0),
                                             LDS(&a_lds[ch * 16 * 32]), 16, 0, 0);
            __builtin_amdgcn_global_load_lds(GLB(gB + (size_t)row * MDL + k0),
                                             LDS(&b_lds[ch * 16 * 32]), 16, 0, 0);
        }
        __syncthreads();

        bf16x8 af[4], bfr[4];
        #pragma unroll
        for (int mi = 0; mi < 4; ++mi)
            af[mi] = *(const bf16x8*)&a_lds[(wr * 64 + mi * 16 + l15) * 32 + quad * 8];
        #pragma unroll
        for (int ni = 0; ni < 4; ++ni)
            bfr[ni] = *(const bf16x8*)&b_lds[(wc * 64 + ni * 16 + l15) * 32 + quad * 8];
        #pragma unroll
        for (int mi = 0; mi < 4; ++mi)
            #pragma unroll
            for (int ni = 0; ni < 4; ++ni)
                acc[mi][ni] = __builtin_amdgcn_mfma_f32_16x16x32_bf16(af[mi], bfr[ni], acc[mi][ni], 0, 0, 0);
        __syncthreads();
    }

    const int bdx = m0 >> 11;
    const int t0 = m0 & (T_SEQ - 1);
    const int bh = bdx * NH + h;

    if (section == 2) {
        // ---- V -> j-permuted image via LDS, linear coalesced out ----
        #pragma unroll
        for (int c = 0; c < 2; ++c) {
            if (wc == c) {
                #pragma unroll
                for (int mi = 0; mi < 4; ++mi)
                    #pragma unroll
                    for (int r = 0; r < 4; ++r) {
                        int p = 16 * quad + 4 * r + mi;       // permuted pos
                        int base = (wr * 8 + (p >> 3)) * 512 + (p & 7);
                        #pragma unroll
                        for (int ni = 0; ni < 4; ++ni)
                            smem[base + (ni * 16 + l15) * 8] = (bf16)acc[mi][ni][r];
                    }
            }
            __syncthreads();
            {
                const int t8 = tid >> 4;
                bf16* vp = Vt + ((size_t)(bh * 32 + (t0 >> 6) + (t8 >> 3))) * 8192
                              + (t8 & 7) * 1024 + c * 512 + (tid & 15) * 32;
                #pragma unroll
                for (int k = 0; k < 4; ++k)
                    *(bf16x8*)(vp + k * 8) = *(const bf16x8*)&smem[tid * 32 + k * 8];
            }
            __syncthreads();
        }
        return;
    }

    float fr_n[2];
    #pragma unroll
    for (int ni = 0; ni < 2; ++ni)
        fr_n[ni] = __expf(-(float)(ni * 16 + l15) * 0.28782313662425573f);

    if (section == 0) {
        // ---- Q: [bh][t][d], RoPE on d<64, all scaled by QSCALE ----
        #pragma unroll
        for (int mi = 0; mi < 4; ++mi) {
            #pragma unroll
            for (int r = 0; r < 4; ++r) {
                int t = t0 + wr * 64 + mi * 16 + quad * 4 + r;
                bf16* orow = Qb + ((size_t)bh * T_SEQ + t) * HD;
                if (wc == 0) {
                    #pragma unroll
                    for (int ni = 0; ni < 2; ++ni) {
                        int d = ni * 16 + l15;
                        float ang = (float)t * fr_n[ni];
                        float sn = __sinf(ang), cs = __cosf(ang);
                        float ev = acc[mi][ni][r];
                        float ov = acc[mi][ni + 2][r];
                        orow[d]      = (bf16)((ev * cs - ov * sn) * QSCALE);
                        orow[d + 32] = (bf16)((ev * sn + ov * cs) * QSCALE);
                    }
                } else {
                    #pragma unroll
                    for (int ni = 0; ni < 4; ++ni)
                        orow[64 + ni * 16 + l15] = (bf16)(acc[mi][ni][r] * QSCALE);
                }
            }
        }
    } else {
        // ---- K -> image via LDS (half = one 64-t jt tile), RoPE fused ----
        #pragma unroll
        for (int c = 0; c < 2; ++c) {
            if (wr == c) {
                #pragma unroll
                for (int mi = 0; mi < 4; ++mi) {
                    #pragma unroll
                    for (int r = 0; r < 4; ++r) {
                        int tl = mi * 16 + quad * 4 + r;
                        int t = t0 + c * 64 + tl;
                        if (wc == 0) {
                            #pragma unroll
                            for (int ni = 0; ni < 2; ++ni) {
                                int d = ni * 16 + l15;
                                float ang = (float)t * fr_n[ni];
                                float sn = __sinf(ang), cs = __cosf(ang);
                                float ev = acc[mi][ni][r];
                                float ov = acc[mi][ni + 2][r];
                                smem[(d >> 3) * 512 + tl * 8 + (d & 7)] = (bf16)(ev * cs - ov * sn);
                                int d2 = d + 32;
                                smem[(d2 >> 3) * 512 + tl * 8 + (d2 & 7)] = (bf16)(ev * sn + ov * cs);
                            }
                        } else {
                            #pragma unroll
                            for (int ni = 0; ni < 4; ++ni) {
                                int d = 64 + ni * 16 + l15;
                                smem[(d >> 3) * 512 + tl * 8 + (d & 7)] = (bf16)acc[mi][ni][r];
                            }
                        }
                    }
                }
            }
            __syncthreads();
            {
                bf16* kp = Kt + ((size_t)(bh * 32 + (t0 >> 6) + c)) * 8192 + tid * 32;
                #pragma unroll
                for (int k = 0; k < 4; ++k)
                    *(bf16x8*)(kp + k * 8) = *(const bf16x8*)&smem[tid * 32 + k * 8];
            }
            __syncthreads();
        }
    }
}

// ---------------------------------------------------------------------------
// Kernel 2: BARRIER-FREE causal flash attention (R9 structure) with:
// (a) XCD-pinned decode bh = bx & 15 -> all 32 blocks of a bh share an XCD;
//     its 2-bh K/V working set (~3 MB) fits the 4 MiB per-XCD L2.
// (b) conflict-free combine: slot stride 33 (odd), b16 writes (bank=col%32),
//     readers row=tid&31 / colgroup=tid>>5 (<=2-way aliasing = free).
// ---------------------------------------------------------------------------
__global__ __launch_bounds__(256, 2) void attn_kernel(
    const bf16* __restrict__ Qb, const bf16* __restrict__ Kt,
    const bf16* __restrict__ Vt, bf16* __restrict__ Ob)
{
    __shared__ bf16 p_lds[4][32 * 72];     // per-wave P [32 rows][64+pad]
    __shared__ bf16 slot[4][128 * 33];     // combine: [col][row], stride 33
    __shared__ float lsl[4][32];           // combine: row sums

    const int tid = threadIdx.x, lane = tid & 63, w = tid >> 6;
    const int quad = lane >> 4, l15 = lane & 15;
    const int bx = blockIdx.x;
    const int bh = bx & 15;                // low bits -> XCD pinning
    const int m  = bx >> 4;                // pair {m, 63-m} of 32-row q-tiles
    const int b = bh >> 3, h = bh & 7;

    const bf16* Kbh = Kt + (size_t)bh * 32 * 8192;
    const bf16* Vbh = Vt + (size_t)bh * 32 * 8192;

    bf16x8 kb[4][4];       // K fragments, full tile, prefetched 1 step ahead
    bf16x8 vb[8];          // V fragments, half-tile batches
    bf16x8 qf[2][4];
    f32x4 Of[2][8];
    float l_r[2][4];

    const bf16* kbase = Kbh + (size_t)quad * 512 + (size_t)l15 * 8;
    const bf16* vbase = Vbh + (size_t)quad * 1024 + (size_t)l15 * 8;

    auto issue_k = [&](int j) {
        const bf16* kt = kbase + (size_t)j * 8192;
        #pragma unroll
        for (int kk = 0; kk < 4; ++kk)
            #pragma unroll
            for (int ni = 0; ni < 4; ++ni)
                kb[kk][ni] = *(const bf16x8*)(kt + kk * 2048 + ni * 128);
    };
    auto issue_v = [&](int j, int half) {
        const bf16* vt = vbase + (size_t)j * 8192 + half * 4096;
        #pragma unroll
        for (int di = 0; di < 8; ++di)
            vb[di] = *(const bf16x8*)(vt + di * 128);
    };

    #pragma unroll 1
    for (int phase = 0; phase < 2; ++phase) {
        const int qt = phase ? m : 63 - m;     // 32-row q-tile index (0..63)
        const int cnt = (qt >> 1) + 1;         // KV 64-tiles needed
        const int dj = qt >> 1;                // diagonal tile

        #pragma unroll
        for (int mi = 0; mi < 2; ++mi) {
            const bf16* qr = Qb + ((size_t)bh * T_SEQ + qt * 32 + mi * 16 + l15) * HD + quad * 8;
            #pragma unroll
            for (int kk = 0; kk < 4; ++kk)
                qf[mi][kk] = *(const bf16x8*)(qr + kk * 32);
            #pragma unroll
            for (int di = 0; di < 8; ++di) Of[mi][di] = (f32x4){0.f, 0.f, 0.f, 0.f};
            #pragma unroll
            for (int r = 0; r < 4; ++r) l_r[mi][r] = 0.f;
        }

        if (w < cnt) issue_k(w);

        #pragma unroll 1
        for (int jt = w; jt < cnt; jt += 4) {
            // ---- S = Q K^T (32 q-rows x 64 kv-cols) ----
            f32x4 sa[2][4] = {};
            #pragma unroll
            for (int kk = 0; kk < 4; ++kk)
                #pragma unroll
                for (int ni = 0; ni < 4; ++ni)
                    #pragma unroll
                    for (int mi = 0; mi < 2; ++mi)
                        sa[mi][ni] = __builtin_amdgcn_mfma_f32_16x16x32_bf16(qf[mi][kk], kb[kk][ni], sa[mi][ni], 0, 0, 0);

            if (jt + 4 < cnt) issue_k(jt + 4);   // next K flies under softmax+PV
            issue_v(jt, 0);                      // current V, first half

            // ---- P = exp2(S), causal mask on the diagonal tile ----
            const bool diag = (jt == dj);
            #pragma unroll
            for (int mi = 0; mi < 2; ++mi) {
                #pragma unroll
                for (int r = 0; r < 4; ++r) {
                    const int rowg = qt * 32 + mi * 16 + quad * 4 + r;
                    float ps = 0.f;
                    bf16x4 pq;
                    #pragma unroll
                    for (int ni = 0; ni < 4; ++ni) {
                        float pv = EXP2(sa[mi][ni][r]);
                        if (diag && (jt * 64 + ni * 16 + l15) > rowg) pv = 0.f;
                        ps += pv;
                        pq[ni] = (bf16)pv;
                    }
                    // j-permuted store: cols l15*4..+3 (one b64)
                    *(bf16x4*)&p_lds[w][(mi * 16 + quad * 4 + r) * 72 + l15 * 4] = pq;
                    l_r[mi][r] += ps;
                }
            }

            // ---- O += P V (V image shares the j-permutation) ----
            bf16x8 pa[2];
            #pragma unroll
            for (int mi = 0; mi < 2; ++mi)
                pa[mi] = *(const bf16x8*)&p_lds[w][(mi * 16 + l15) * 72 + quad * 8];
            #pragma unroll
            for (int di = 0; di < 8; ++di)
                #pragma unroll
                for (int mi = 0; mi < 2; ++mi)
                    Of[mi][di] = __builtin_amdgcn_mfma_f32_16x16x32_bf16(pa[mi], vb[di], Of[mi][di], 0, 0, 0);

            issue_v(jt, 1);                      // second half
            #pragma unroll
            for (int mi = 0; mi < 2; ++mi)
                pa[mi] = *(const bf16x8*)&p_lds[w][(mi * 16 + l15) * 72 + 32 + quad * 8];
            #pragma unroll
            for (int di = 0; di < 8; ++di)
                #pragma unroll
                for (int mi = 0; mi < 2; ++mi)
                    Of[mi][di] = __builtin_amdgcn_mfma_f32_16x16x32_bf16(pa[mi], vb[di], Of[mi][di], 0, 0, 0);
        }

        // ---- intra-block combine of 4 split partials, direct Ob store ----
        __syncthreads();                         // all waves done with steps
        #pragma unroll
        for (int mi = 0; mi < 2; ++mi)
            #pragma unroll
            for (int di = 0; di < 8; ++di) {
                const int col = di * 16 + l15;
                #pragma unroll
                for (int r = 0; r < 4; ++r)
                    slot[w][col * 33 + mi * 16 + quad * 4 + r] = (bf16)Of[mi][di][r];
            }
        #pragma unroll
        for (int mi = 0; mi < 2; ++mi)
            #pragma unroll
            for (int r = 0; r < 4; ++r) {
                float ls = l_r[mi][r];
                ls += __shfl_xor(ls, 1); ls += __shfl_xor(ls, 2);
                ls += __shfl_xor(ls, 4); ls += __shfl_xor(ls, 8);
                if (l15 == 0) lsl[w][mi * 16 + quad * 4 + r] = ls;
            }
        __syncthreads();                         // slots visible
        {
            const int row = tid & 31;            // 0..31
            const int g = tid >> 5;              // 8 groups of 16 d-cols
            float av[16] = {};
            float l = 0.f;
            #pragma unroll
            for (int s = 0; s < 4; ++s) {
                l += lsl[s][row];
                #pragma unroll
                for (int c = 0; c < 16; ++c)
                    av[c] += (float)slot[s][(g * 16 + c) * 33 + row];
            }
            const float inv = 1.f / l;
            const int t = qt * 32 + row;
            bf16* op = Ob + ((size_t)(b * T_SEQ + t) * NH + h) * HD + g * 16;
            bf16x8 o0, o1;
            #pragma unroll
            for (int c = 0; c < 8; ++c) { o0[c] = (bf16)(av[c] * inv); o1[c] = (bf16)(av[c + 8] * inv); }
            *(bf16x8*)op = o0;
            *(bf16x8*)(op + 8) = o1;
        }
        __syncthreads();                         // slots reusable next phase
    }
}

// ---------------------------------------------------------------------------
// Kernel 3: output projection, m97 structure. R = Ob @ Wot^T, fp32 out.
// ---------------------------------------------------------------------------
__global__ __launch_bounds__(256) void out_proj_kernel(
    const bf16* __restrict__ Ob, const bf16* __restrict__ Wot,
    float* __restrict__ out)
{
    __shared__ bf16 a_lds[128 * 32];
    __shared__ bf16 b_lds[128 * 32];

    const int tid = threadIdx.x, bx = blockIdx.x;
    const int nt = bx & 7, mt = bx >> 3;
    const int n0 = nt * 128, m0 = mt * 128;

    const int lane = tid & 63, w = tid >> 6;
    const int quad = lane >> 4, l15 = lane & 15;
    const int wr = w >> 1, wc = w & 1;
    const int lrow = lane >> 2, lsub = lane & 3;

    const bf16* gA = Ob  + (size_t)m0 * MDL + lsub * 8;
    const bf16* gB = Wot + (size_t)n0 * MDL + lsub * 8;

    f32x4 acc[4][4] = {};

    for (int k0 = 0; k0 < MDL; k0 += 32) {
        #pragma unroll
        for (int i = 0; i < 2; ++i) {
            const int ch = w * 2 + i;
            const int row = ch * 16 + lrow;
            __builtin_amdgcn_global_load_lds(GLB(gA + (size_t)row * MDL + k0),
                                             LDS(&a_lds[ch * 16 * 32]), 16, 0, 0);
            __builtin_amdgcn_global_load_lds(GLB(gB + (size_t)row * MDL + k0),
                                             LDS(&b_lds[ch * 16 * 32]), 16, 0, 0);
        }
        __syncthreads();

        bf16x8 af[4], bfr[4];
        #pragma unroll
        for (int mi = 0; mi < 4; ++mi)
            af[mi] = *(const bf16x8*)&a_lds[(wr * 64 + mi * 16 + l15) * 32 + quad * 8];
        #pragma unroll
        for (int ni = 0; ni < 4; ++ni)
            bfr[ni] = *(const bf16x8*)&b_lds[(wc * 64 + ni * 16 + l15) * 32 + quad * 8];
        #pragma unroll
        for (int mi = 0; mi < 4; ++mi)
            #pragma unroll
            for (int ni = 0; ni < 4; ++ni)
                acc[mi][ni] = __builtin_amdgcn_mfma_f32_16x16x32_bf16(af[mi], bfr[ni], acc[mi][ni], 0, 0, 0);
        __syncthreads();
    }

    #pragma unroll
    for (int mi = 0; mi < 4; ++mi)
        #pragma unroll
        for (int r = 0; r < 4; ++r) {
            int row_g = m0 + wr * 64 + mi * 16 + quad * 4 + r;
            float* crow = out + (size_t)row_g * MDL + n0;
            #pragma unroll
            for (int ni = 0; ni < 4; ++ni)
                crow[wc * 64 + ni * 16 + l15] = acc[mi][ni][r];
        }
}

// ---------------------------------------------------------------------------
extern "C" void kernel_launch(void* const* d_in, const int* in_sizes, int n_in,
                              void* d_out, int out_size, void* d_ws, size_t ws_size,
                              hipStream_t stream) {
    const float* x  = (const float*)d_in[0];
    const float* wq = (const float*)d_in[1];
    const float* wk = (const float*)d_in[2];
    const float* wv = (const float*)d_in[3];
    const float* wo = (const float*)d_in[4];
    float* out = (float*)d_out;

    const size_t NTOK = (size_t)2 * NH * T_SEQ * HD;  // 4,194,304 elems
    bf16*  Qb  = (bf16*)d_ws;
    bf16*  Kt  = Qb + NTOK;
    bf16*  Vt  = Kt + NTOK;
    bf16*  Ob  = Vt + NTOK;
    bf16*  Wot = Ob + NTOK;                           // 1 M elems

    // xb / Wt scratch live inside d_out (16 MB) — dead before out_proj writes.
    bf16* xbuf = (bf16*)d_out;
    bf16* Wt   = xbuf + (size_t)4096 * MDL;

    prep_kernel<<<3072, 256, 0, stream>>>(x, wq, wk, wv, wo, xbuf, Wt, Wot);
    qkv_rope_kernel<<<768, 256, 0, stream>>>(xbuf, Wt, Qb, Kt, Vt);
    attn_kernel<<<512, 256, 0, stream>>>(Qb, Kt, Vt, Ob);
    out_proj_kernel<<<256, 256, 0, stream>>>(Ob, Wot, out);
}